// Round 13
// baseline (5374.326 us; speedup 1.0000x reference)
//
#include <hip/hip_runtime.h>

#define TT 512
#define BB 1024
#define FF 32
#define HH 64
#define GG 256   // 4*H gates per direction

// Static device scratch (ws_size-independent). Fully overwritten every call.
__device__ float g_h1[(size_t)TT * BB * 2 * HH];   // [T][B][128] layer-1 input
__device__ float g_pre0[(size_t)2 * TT * BB * GG]; // [dir][T][B][256] layer-0 pre-gates
__device__ float g_pre1[(size_t)TT * BB * GG];     // [T][B][256] layer-1 fwd pre-gates
__device__ float g_hf[(size_t)BB * HH];            // [B][64] final fwd h of layer1

__device__ __forceinline__ float fsigm(float x) {
    float e = __builtin_amdgcn_exp2f(x * -1.44269504088896f);
    return __builtin_amdgcn_rcpf(1.0f + e);
}
__device__ __forceinline__ float ftanh(float x) {
    float e = __builtin_amdgcn_exp2f(x * -2.88539008177793f);
    return 2.0f * __builtin_amdgcn_rcpf(1.0f + e) - 1.0f;
}
// Wave-uniform broadcast via v_readlane (VALU, zero LDS-pipe cost).
__device__ __forceinline__ float rlane(float v, int l) {
    return __int_as_float(__builtin_amdgcn_readlane(__float_as_int(v), l));
}

#define FMA4(c, s, b) do { c.x += (s)*(b).x; c.y += (s)*(b).y; \
                           c.z += (s)*(b).z; c.w += (s)*(b).w; } while (0)

// ---------------------------------------------------------------------------
// Layer-0 input pre-gates — original (best measured).
// ---------------------------------------------------------------------------
__global__ __launch_bounds__(256, 4) void pre_gemm0(
    const float* __restrict__ x,      // [B][T][F]
    const float* __restrict__ w_ih,   // [2][G][F]
    const float* __restrict__ b_ih,
    const float* __restrict__ b_hh)
{
    const int tid = threadIdx.x;          // gate
    const int b   = blockIdx.x >> 1;
    const int dir = blockIdx.x & 1;

    __shared__ __align__(16) float4 w4[8 * 256];    // [kq][gate], 32 KB
    __shared__ __align__(16) float xbuf[2][256];    // 8 t-rows x 32 f, dbuf

    const float4* wsrc = (const float4*)(w_ih + ((size_t)dir * GG + tid) * FF);
#pragma unroll
    for (int kq = 0; kq < 8; ++kq) w4[kq * 256 + tid] = wsrc[kq];
    const float bias = b_ih[dir * GG + tid] + b_hh[dir * GG + tid];

    const float* xbase = x + (size_t)b * TT * FF;
    xbuf[0][tid] = xbase[tid];            // tile 0 (rows 0..7), coalesced
    const size_t OS = (size_t)BB * GG;

    for (int tc = 0; tc < 64; ++tc) {
        const int cur = tc & 1;
        __syncthreads();   // xbuf[cur] ready; prev reads of xbuf[1-cur] done

        float vnext = 0.f;
        if (tc + 1 < 64) vnext = xbase[(tc + 1) * 256 + tid];   // coalesced

        float a0 = bias, a1 = bias, a2 = bias, a3 = bias,
              a4 = bias, a5 = bias, a6 = bias, a7 = bias;
#pragma unroll
        for (int kq = 0; kq < 8; ++kq) {
            float4 wq = w4[kq * 256 + tid];
            const float4* xr = (const float4*)xbuf[cur];
            float4 q;
            q = xr[0 * 8 + kq]; a0 += q.x*wq.x + q.y*wq.y + q.z*wq.z + q.w*wq.w;
            q = xr[1 * 8 + kq]; a1 += q.x*wq.x + q.y*wq.y + q.z*wq.z + q.w*wq.w;
            q = xr[2 * 8 + kq]; a2 += q.x*wq.x + q.y*wq.y + q.z*wq.z + q.w*wq.w;
            q = xr[3 * 8 + kq]; a3 += q.x*wq.x + q.y*wq.y + q.z*wq.z + q.w*wq.w;
            q = xr[4 * 8 + kq]; a4 += q.x*wq.x + q.y*wq.y + q.z*wq.z + q.w*wq.w;
            q = xr[5 * 8 + kq]; a5 += q.x*wq.x + q.y*wq.y + q.z*wq.z + q.w*wq.w;
            q = xr[6 * 8 + kq]; a6 += q.x*wq.x + q.y*wq.y + q.z*wq.z + q.w*wq.w;
            q = xr[7 * 8 + kq]; a7 += q.x*wq.x + q.y*wq.y + q.z*wq.z + q.w*wq.w;
        }
        float* op = g_pre0 + (((size_t)dir * TT + tc * 8) * BB + b) * GG + tid;
        op[0] = a0; op[1 * OS] = a1; op[2 * OS] = a2; op[3 * OS] = a3;
        op[4 * OS] = a4; op[5 * OS] = a5; op[6 * OS] = a6; op[7 * OS] = a7;

        if (tc + 1 < 64) xbuf[1 - cur][tid] = vnext;
    }
}

// ---------------------------------------------------------------------------
// Recurrent scan v11: R12 per-wave structure (i/f pinned 128 VGPR, g/o in
// shared conflict-free LDS, B1) packed FOUR WAVES PER BLOCK sharing one wgo
// buffer. R12's null (990us from two different instr mixes, VALUBusy 73-81%)
// proved the scan is LATENCY-bound at 1 wave/SIMD; R8's occupancy poison was
// the L2-remat traffic, now gone (g/o from LDS, i/f from regs). 4-wave
// blocks cut LDS/wave 4x: VGPR 152x3<=512, LDS 32KBx3<=160KB -> 3 blocks/CU
// = 3 waves/SIMD, and scan<0>'s 2048 waves run in ONE pass (was two).
// L=0: grid 512 (bid&1=dir, 4 batches/block). L=1: grid 256.
// ---------------------------------------------------------------------------
#define PINQ(wq) \
    asm volatile("" : "+v"(wq.x), "+v"(wq.y), "+v"(wq.z), "+v"(wq.w))

template <int L>
__global__ __launch_bounds__(256, 2) void lstm_scan(
    const float* __restrict__ w_hh)   // [2][G][64]
{
    const int tid = threadIdx.x;
    const int l   = tid & 63;
    const int wid = tid >> 6;
    const int dir = (L == 0) ? (blockIdx.x & 1) : 0;
    const int b   = ((L == 0) ? (int)(blockIdx.x >> 1) : (int)blockIdx.x) * 4 + wid;

    const float* wbase = w_hh + (size_t)dir * GG * HH;

    // g/o rows -> shared LDS: wgo[(gc*16+q)*64 + l] = W[(2+gc)*64 + l][quad q].
    // Cooperative staging: wave wid stages quads [wid*4, wid*4+4).
    __shared__ __align__(16) float4 wgo[2 * 16 * 64];   // 32 KB, shared by 4 waves
    {
        const float4* pg_ = (const float4*)(wbase + (size_t)(128 + l) * HH);
        const float4* po_ = (const float4*)(wbase + (size_t)(192 + l) * HH);
#pragma unroll
        for (int i = 0; i < 4; ++i) {
            const int q = wid * 4 + i;
            wgo[q * 64 + l]        = pg_[q];
            wgo[(16 + q) * 64 + l] = po_[q];
        }
    }

    // i/f rows: named quads, pinned resident (128 VGPR, R9-proven).
    const float4* pi_ = (const float4*)(wbase + (size_t)(0  + l) * HH);
    const float4* pf_ = (const float4*)(wbase + (size_t)(64 + l) * HH);
    float4 wi0 = pi_[0],  wi1 = pi_[1],  wi2 = pi_[2],  wi3 = pi_[3],
           wi4 = pi_[4],  wi5 = pi_[5],  wi6 = pi_[6],  wi7 = pi_[7],
           wi8 = pi_[8],  wi9 = pi_[9],  wi10 = pi_[10], wi11 = pi_[11],
           wi12 = pi_[12], wi13 = pi_[13], wi14 = pi_[14], wi15 = pi_[15];
    float4 wf0 = pf_[0],  wf1 = pf_[1],  wf2 = pf_[2],  wf3 = pf_[3],
           wf4 = pf_[4],  wf5 = pf_[5],  wf6 = pf_[6],  wf7 = pf_[7],
           wf8 = pf_[8],  wf9 = pf_[9],  wf10 = pf_[10], wf11 = pf_[11],
           wf12 = pf_[12], wf13 = pf_[13], wf14 = pf_[14], wf15 = pf_[15];
    PINQ(wi0);  PINQ(wi1);  PINQ(wi2);  PINQ(wi3);
    PINQ(wi4);  PINQ(wi5);  PINQ(wi6);  PINQ(wi7);
    PINQ(wi8);  PINQ(wi9);  PINQ(wi10); PINQ(wi11);
    PINQ(wi12); PINQ(wi13); PINQ(wi14); PINQ(wi15);
    PINQ(wf0);  PINQ(wf1);  PINQ(wf2);  PINQ(wf3);
    PINQ(wf4);  PINQ(wf5);  PINQ(wf6);  PINQ(wf7);
    PINQ(wf8);  PINQ(wf9);  PINQ(wf10); PINQ(wf11);
    PINQ(wf12); PINQ(wf13); PINQ(wf14); PINQ(wf15);

    __syncthreads();   // wgo fully staged across the 4 waves

    const float* pre = (L == 0) ? (g_pre0 + (size_t)dir * TT * BB * GG) : g_pre1;

    float c = 0.f, h = 0.f;

    // 2-deep pre-gate prefetch pipeline (explicit register rotation).
    const int t0 = dir ? (TT - 1) : 0;
    const int t1 = dir ? (TT - 2) : 1;
    const float* pp0 = pre + ((size_t)t0 * BB + b) * GG;
    const float* pp1 = pre + ((size_t)t1 * BB + b) * GG;
    float ci0 = pp0[l], cf0 = pp0[64 + l], cg0 = pp0[128 + l], co0 = pp0[192 + l];
    float ci1 = pp1[l], cf1 = pp1[64 + l], cg1 = pp1[128 + l], co1 = pp1[192 + l];

    for (int s = 0; s < TT; ++s) {
        const int t = dir ? (TT - 1 - s) : s;

        // Issue prefetch for step s+2 (consumed two iterations from now).
        float ni = 0.f, nf = 0.f, ng = 0.f, no_ = 0.f;
        if (s + 2 < TT) {
            const int tn = dir ? (TT - 3 - s) : (s + 2);
            const float* np = pre + ((size_t)tn * BB + b) * GG;
            ni = np[l]; nf = np[64 + l]; ng = np[128 + l]; no_ = np[192 + l];
        }

        float ai = ci0, af = cf0, ag = cg0, ao = co0;

#define STEPQ(q) do {                                                        \
        const float4 wgq = wgo[(q) * 64 + l];                                \
        const float4 woq = wgo[(16 + (q)) * 64 + l];                         \
        float s0 = rlane(h, 4*q+0), s1 = rlane(h, 4*q+1),                    \
              s2 = rlane(h, 4*q+2), s3 = rlane(h, 4*q+3);                    \
        ai += s0*wi##q.x + s1*wi##q.y + s2*wi##q.z + s3*wi##q.w;             \
        af += s0*wf##q.x + s1*wf##q.y + s2*wf##q.z + s3*wf##q.w;             \
        ag += s0*wgq.x + s1*wgq.y + s2*wgq.z + s3*wgq.w;                     \
        ao += s0*woq.x + s1*woq.y + s2*woq.z + s3*woq.w;                     \
    } while (0)

        STEPQ(0);  STEPQ(1);  STEPQ(2);  STEPQ(3);
        STEPQ(4);  STEPQ(5);  STEPQ(6);  STEPQ(7);
        STEPQ(8);  STEPQ(9);  STEPQ(10); STEPQ(11);
        STEPQ(12); STEPQ(13); STEPQ(14); STEPQ(15);
#undef STEPQ

        const float ig = fsigm(ai);
        const float fg = fsigm(af);
        const float gg = ftanh(ag);
        const float og = fsigm(ao);
        c = fg * c + ig * gg;
        h = og * ftanh(c);

        if (L == 0) {
            g_h1[((size_t)t * BB + b) * (2 * HH) + dir * HH + l] = h;  // coalesced 256B
        } else {
            if (s == TT - 1) g_hf[(size_t)b * HH + l] = h;
        }

        // Rotate the prefetch pipeline.
        ci0 = ci1; cf0 = cf1; cg0 = cg1; co0 = co1;
        ci1 = ni;  cf1 = nf;  cg1 = ng;  co1 = no_;
    }
}

// ---------------------------------------------------------------------------
// Layer-1 forward input pre-gates, v2.1 (proven correct in R8/R9): tiled GEMM.
// OUT[M=TT*BB][256] = H1[M][128] @ W^T + bias; OUT row m = t*BB+b.
// Tile 64m x 64n, K=128 one-shot: A row-major (+132-dword pad), B transposed
// [k][n] (+68-dword pad). Thread (ty,tx) computes 4m x 4n. 67 KB LDS.
// ---------------------------------------------------------------------------
__global__ __launch_bounds__(256, 2) void pre_gemm1(
    const float* __restrict__ w_ih,   // [2][G][128] (dir 0 used)
    const float* __restrict__ b_ih,
    const float* __restrict__ b_hh)
{
    __shared__ __align__(16) float As[64 * 132];   // [m][k], pad 132
    __shared__ __align__(16) float Bs[128 * 68];   // [k][n], pad 68

    const int tid   = threadIdx.x;
    const int mbase = (int)(blockIdx.x >> 2) * 64;
    const int n0    = (int)(blockIdx.x & 3) * 64;

    // Stage A: 64 rows x 32 k-quads = 2048 quads, 8 iters, coalesced.
#pragma unroll
    for (int i = 0; i < 8; ++i) {
        const int qid = tid + 256 * i;
        const int r = qid >> 5, q = qid & 31;
        float4 v = *(const float4*)(g_h1 + (size_t)(mbase + r) * 128 + q * 4);
        *(float4*)(&As[r * 132 + q * 4]) = v;
    }
    // Stage B transposed: 64 n-rows x 32 k-quads = 2048 quads, 8 iters.
#pragma unroll
    for (int i = 0; i < 8; ++i) {
        const int qid = tid + 256 * i;
        const int r = qid >> 5, q = qid & 31;   // r = local gate, q = k-quad
        float4 v = *(const float4*)(w_ih + (size_t)(n0 + r) * 128 + q * 4);
        Bs[(q * 4 + 0) * 68 + r] = v.x;
        Bs[(q * 4 + 1) * 68 + r] = v.y;
        Bs[(q * 4 + 2) * 68 + r] = v.z;
        Bs[(q * 4 + 3) * 68 + r] = v.w;
    }
    __syncthreads();

    const int tx = tid & 15, ty = tid >> 4;

    float4 c0 = make_float4(0.f, 0.f, 0.f, 0.f);
    float4 c1 = c0, c2 = c0, c3 = c0;

#pragma unroll 8
    for (int kq = 0; kq < 32; ++kq) {
        const float4 a0 = *(const float4*)&As[(ty * 4 + 0) * 132 + kq * 4];
        const float4 a1 = *(const float4*)&As[(ty * 4 + 1) * 132 + kq * 4];
        const float4 a2 = *(const float4*)&As[(ty * 4 + 2) * 132 + kq * 4];
        const float4 a3 = *(const float4*)&As[(ty * 4 + 3) * 132 + kq * 4];
        const float4 b0 = *(const float4*)&Bs[(kq * 4 + 0) * 68 + tx * 4];
        const float4 b1 = *(const float4*)&Bs[(kq * 4 + 1) * 68 + tx * 4];
        const float4 b2 = *(const float4*)&Bs[(kq * 4 + 2) * 68 + tx * 4];
        const float4 b3 = *(const float4*)&Bs[(kq * 4 + 3) * 68 + tx * 4];
        FMA4(c0, a0.x, b0); FMA4(c0, a0.y, b1); FMA4(c0, a0.z, b2); FMA4(c0, a0.w, b3);
        FMA4(c1, a1.x, b0); FMA4(c1, a1.y, b1); FMA4(c1, a1.z, b2); FMA4(c1, a1.w, b3);
        FMA4(c2, a2.x, b0); FMA4(c2, a2.y, b1); FMA4(c2, a2.z, b2); FMA4(c2, a2.w, b3);
        FMA4(c3, a3.x, b0); FMA4(c3, a3.y, b1); FMA4(c3, a3.z, b2); FMA4(c3, a3.w, b3);
    }

    float4 bias4;
    bias4.x = b_ih[n0 + tx * 4 + 0] + b_hh[n0 + tx * 4 + 0];
    bias4.y = b_ih[n0 + tx * 4 + 1] + b_hh[n0 + tx * 4 + 1];
    bias4.z = b_ih[n0 + tx * 4 + 2] + b_hh[n0 + tx * 4 + 2];
    bias4.w = b_ih[n0 + tx * 4 + 3] + b_hh[n0 + tx * 4 + 3];

    FMA4(c0, 1.f, bias4); FMA4(c1, 1.f, bias4);
    FMA4(c2, 1.f, bias4); FMA4(c3, 1.f, bias4);

    float* ob = g_pre1 + (size_t)(mbase + ty * 4) * GG + n0 + tx * 4;
    *(float4*)(ob + 0 * (size_t)GG) = c0;
    *(float4*)(ob + 1 * (size_t)GG) = c1;
    *(float4*)(ob + 2 * (size_t)GG) = c2;
    *(float4*)(ob + 3 * (size_t)GG) = c3;
}

// ---------------------------------------------------------------------------
// Layer 1 backward single step (zero state on h1[T-1]) + FC head (unchanged).
// ---------------------------------------------------------------------------
#define FMAC4(W, P0, P1, P2, P3, K) do{                                   \
    float4 v_;                                                           \
    v_ = (P0)[K]; acc0 += W.x*v_.x; acc0 += W.y*v_.y; acc0 += W.z*v_.z; acc0 += W.w*v_.w; \
    v_ = (P1)[K]; acc1 += W.x*v_.x; acc1 += W.y*v_.y; acc1 += W.z*v_.z; acc1 += W.w*v_.w; \
    v_ = (P2)[K]; acc2 += W.x*v_.x; acc2 += W.y*v_.y; acc2 += W.z*v_.z; acc2 += W.w*v_.w; \
    v_ = (P3)[K]; acc3 += W.x*v_.x; acc3 += W.y*v_.y; acc3 += W.z*v_.z; acc3 += W.w*v_.w; \
}while(0)

__global__ __launch_bounds__(256, 2) void lstm_final(
    const float* __restrict__ w_ih,   // [2][G][128] (dir 1)
    const float* __restrict__ b_ih,
    const float* __restrict__ b_hh,
    const float* __restrict__ fc_w,   // [2][128]
    const float* __restrict__ fc_b,   // [2]
    float* __restrict__ out)          // [B][2]
{
    const int tid = threadIdx.x;
    const int b0  = blockIdx.x * 4;

    __shared__ __align__(16) float x_lds[4][128];
    __shared__ __align__(16) float gact[4][GG];
    __shared__ __align__(16) float last[4][128];

#pragma unroll
    for (int r = 0; r < 2; ++r) {
        int idx = tid + r * 256;
        int b = idx >> 7, col = idx & 127;
        x_lds[b][col] = g_h1[((size_t)(TT - 1) * BB + (b0 + b)) * 128 + col];
    }

    const float4* p = (const float4*)(w_ih + ((size_t)GG + tid) * 128);
    float4 w0 = p[0],  w1 = p[1],  w2 = p[2],  w3 = p[3],  w4 = p[4],  w5 = p[5],
           w6 = p[6],  w7 = p[7],  w8 = p[8],  w9 = p[9],  w10 = p[10], w11 = p[11],
           w12 = p[12], w13 = p[13], w14 = p[14], w15 = p[15], w16 = p[16], w17 = p[17],
           w18 = p[18], w19 = p[19], w20 = p[20], w21 = p[21], w22 = p[22], w23 = p[23],
           w24 = p[24], w25 = p[25], w26 = p[26], w27 = p[27], w28 = p[28], w29 = p[29],
           w30 = p[30], w31 = p[31];
    const float bias = b_ih[GG + tid] + b_hh[GG + tid];
    __syncthreads();

    const float4* xb0 = (const float4*)x_lds[0];
    const float4* xb1 = (const float4*)x_lds[1];
    const float4* xb2 = (const float4*)x_lds[2];
    const float4* xb3 = (const float4*)x_lds[3];

    float acc0 = bias, acc1 = bias, acc2 = bias, acc3 = bias;
    FMAC4(w0, xb0, xb1, xb2, xb3, 0);   FMAC4(w1, xb0, xb1, xb2, xb3, 1);
    FMAC4(w2, xb0, xb1, xb2, xb3, 2);   FMAC4(w3, xb0, xb1, xb2, xb3, 3);
    FMAC4(w4, xb0, xb1, xb2, xb3, 4);   FMAC4(w5, xb0, xb1, xb2, xb3, 5);
    FMAC4(w6, xb0, xb1, xb2, xb3, 6);   FMAC4(w7, xb0, xb1, xb2, xb3, 7);
    FMAC4(w8, xb0, xb1, xb2, xb3, 8);   FMAC4(w9, xb0, xb1, xb2, xb3, 9);
    FMAC4(w10, xb0, xb1, xb2, xb3, 10); FMAC4(w11, xb0, xb1, xb2, xb3, 11);
    FMAC4(w12, xb0, xb1, xb2, xb3, 12); FMAC4(w13, xb0, xb1, xb2, xb3, 13);
    FMAC4(w14, xb0, xb1, xb2, xb3, 14); FMAC4(w15, xb0, xb1, xb2, xb3, 15);
    FMAC4(w16, xb0, xb1, xb2, xb3, 16); FMAC4(w17, xb0, xb1, xb2, xb3, 17);
    FMAC4(w18, xb0, xb1, xb2, xb3, 18); FMAC4(w19, xb0, xb1, xb2, xb3, 19);
    FMAC4(w20, xb0, xb1, xb2, xb3, 20); FMAC4(w21, xb0, xb1, xb2, xb3, 21);
    FMAC4(w22, xb0, xb1, xb2, xb3, 22); FMAC4(w23, xb0, xb1, xb2, xb3, 23);
    FMAC4(w24, xb0, xb1, xb2, xb3, 24); FMAC4(w25, xb0, xb1, xb2, xb3, 25);
    FMAC4(w26, xb0, xb1, xb2, xb3, 26); FMAC4(w27, xb0, xb1, xb2, xb3, 27);
    FMAC4(w28, xb0, xb1, xb2, xb3, 28); FMAC4(w29, xb0, xb1, xb2, xb3, 29);
    FMAC4(w30, xb0, xb1, xb2, xb3, 30); FMAC4(w31, xb0, xb1, xb2, xb3, 31);

    const bool is_g = ((tid >> 6) == 2);
    gact[0][tid] = is_g ? ftanh(acc0) : fsigm(acc0);
    gact[1][tid] = is_g ? ftanh(acc1) : fsigm(acc1);
    gact[2][tid] = is_g ? ftanh(acc2) : fsigm(acc2);
    gact[3][tid] = is_g ? ftanh(acc3) : fsigm(acc3);
    __syncthreads();

    {
        const int cb = tid >> 6, cj = tid & 63;
        float ig = gact[cb][cj];
        float gg = gact[cb][2 * HH + cj];
        float og = gact[cb][3 * HH + cj];
        float c = ig * gg;
        float h = og * ftanh(c);
        last[cb][HH + cj] = h;
        last[cb][cj] = g_hf[(size_t)(b0 + cb) * HH + cj];
    }
    __syncthreads();

    if (tid < 8) {
        int b = tid >> 1, o = tid & 1;
        float a = fc_b[o];
#pragma unroll
        for (int j = 0; j < 128; ++j) a += fc_w[o * 128 + j] * last[b][j];
        out[(size_t)(b0 + b) * 2 + o] = a;
    }
}

extern "C" void kernel_launch(void* const* d_in, const int* in_sizes, int n_in,
                              void* d_out, int out_size, void* d_ws, size_t ws_size,
                              hipStream_t stream) {
    const float* x     = (const float*)d_in[0];
    const float* w_ih0 = (const float*)d_in[1];
    const float* w_hh0 = (const float*)d_in[2];
    const float* b_ih0 = (const float*)d_in[3];
    const float* b_hh0 = (const float*)d_in[4];
    const float* w_ih1 = (const float*)d_in[5];
    const float* w_hh1 = (const float*)d_in[6];
    const float* b_ih1 = (const float*)d_in[7];
    const float* b_hh1 = (const float*)d_in[8];
    const float* fc_w  = (const float*)d_in[9];
    const float* fc_b  = (const float*)d_in[10];
    float* out = (float*)d_out;

    pre_gemm0<<<2048, 256, 0, stream>>>(x, w_ih0, b_ih0, b_hh0);
    lstm_scan<0><<<512, 256, 0, stream>>>(w_hh0);
    pre_gemm1<<<32768, 256, 0, stream>>>(w_ih1, b_ih1, b_hh1);
    lstm_scan<1><<<256, 256, 0, stream>>>(w_hh1);
    lstm_final<<<256, 256, 0, stream>>>(w_ih1, b_ih1, b_hh1, fc_w, fc_b, out);
}

// Round 14
// 2996.025 us; speedup vs baseline: 1.7938x; 1.7938x over previous
//
#include <hip/hip_runtime.h>

#define TT 512
#define BB 1024
#define FF 32
#define HH 64
#define GG 256   // 4*H gates per direction

// Static device scratch (ws_size-independent). Fully overwritten every call.
__device__ float g_h1[(size_t)TT * BB * 2 * HH];   // [T][B][128] layer-1 input
__device__ float g_pre0[(size_t)2 * TT * BB * GG]; // [dir][T][B][256] layer-0 pre-gates
__device__ float g_pre1[(size_t)TT * BB * GG];     // [T][B][256] layer-1 fwd pre-gates
__device__ float g_hf[(size_t)BB * HH];            // [B][64] final fwd h of layer1

__device__ __forceinline__ float fsigm(float x) {
    float e = __builtin_amdgcn_exp2f(x * -1.44269504088896f);
    return __builtin_amdgcn_rcpf(1.0f + e);
}
__device__ __forceinline__ float ftanh(float x) {
    float e = __builtin_amdgcn_exp2f(x * -2.88539008177793f);
    return 2.0f * __builtin_amdgcn_rcpf(1.0f + e) - 1.0f;
}
// Wave-uniform broadcast via v_readlane (VALU, zero LDS-pipe cost).
__device__ __forceinline__ float rlane(float v, int l) {
    return __int_as_float(__builtin_amdgcn_readlane(__float_as_int(v), l));
}

#define FMA4(c, s, b) do { c.x += (s)*(b).x; c.y += (s)*(b).y; \
                           c.z += (s)*(b).z; c.w += (s)*(b).w; } while (0)

// ---------------------------------------------------------------------------
// Layer-0 input pre-gates — original (best measured).
// ---------------------------------------------------------------------------
__global__ __launch_bounds__(256, 4) void pre_gemm0(
    const float* __restrict__ x,      // [B][T][F]
    const float* __restrict__ w_ih,   // [2][G][F]
    const float* __restrict__ b_ih,
    const float* __restrict__ b_hh)
{
    const int tid = threadIdx.x;          // gate
    const int b   = blockIdx.x >> 1;
    const int dir = blockIdx.x & 1;

    __shared__ __align__(16) float4 w4[8 * 256];    // [kq][gate], 32 KB
    __shared__ __align__(16) float xbuf[2][256];    // 8 t-rows x 32 f, dbuf

    const float4* wsrc = (const float4*)(w_ih + ((size_t)dir * GG + tid) * FF);
#pragma unroll
    for (int kq = 0; kq < 8; ++kq) w4[kq * 256 + tid] = wsrc[kq];
    const float bias = b_ih[dir * GG + tid] + b_hh[dir * GG + tid];

    const float* xbase = x + (size_t)b * TT * FF;
    xbuf[0][tid] = xbase[tid];            // tile 0 (rows 0..7), coalesced
    const size_t OS = (size_t)BB * GG;

    for (int tc = 0; tc < 64; ++tc) {
        const int cur = tc & 1;
        __syncthreads();   // xbuf[cur] ready; prev reads of xbuf[1-cur] done

        float vnext = 0.f;
        if (tc + 1 < 64) vnext = xbase[(tc + 1) * 256 + tid];   // coalesced

        float a0 = bias, a1 = bias, a2 = bias, a3 = bias,
              a4 = bias, a5 = bias, a6 = bias, a7 = bias;
#pragma unroll
        for (int kq = 0; kq < 8; ++kq) {
            float4 wq = w4[kq * 256 + tid];
            const float4* xr = (const float4*)xbuf[cur];
            float4 q;
            q = xr[0 * 8 + kq]; a0 += q.x*wq.x + q.y*wq.y + q.z*wq.z + q.w*wq.w;
            q = xr[1 * 8 + kq]; a1 += q.x*wq.x + q.y*wq.y + q.z*wq.z + q.w*wq.w;
            q = xr[2 * 8 + kq]; a2 += q.x*wq.x + q.y*wq.y + q.z*wq.z + q.w*wq.w;
            q = xr[3 * 8 + kq]; a3 += q.x*wq.x + q.y*wq.y + q.z*wq.z + q.w*wq.w;
            q = xr[4 * 8 + kq]; a4 += q.x*wq.x + q.y*wq.y + q.z*wq.z + q.w*wq.w;
            q = xr[5 * 8 + kq]; a5 += q.x*wq.x + q.y*wq.y + q.z*wq.z + q.w*wq.w;
            q = xr[6 * 8 + kq]; a6 += q.x*wq.x + q.y*wq.y + q.z*wq.z + q.w*wq.w;
            q = xr[7 * 8 + kq]; a7 += q.x*wq.x + q.y*wq.y + q.z*wq.z + q.w*wq.w;
        }
        float* op = g_pre0 + (((size_t)dir * TT + tc * 8) * BB + b) * GG + tid;
        op[0] = a0; op[1 * OS] = a1; op[2 * OS] = a2; op[3 * OS] = a3;
        op[4 * OS] = a4; op[5 * OS] = a5; op[6 * OS] = a6; op[7 * OS] = a7;

        if (tc + 1 < 64) xbuf[1 - cur][tid] = vnext;
    }
}

// ---------------------------------------------------------------------------
// Recurrent scan v12: 1-wave blocks, (64,1) — the PROVEN allocator envelope
// (R9:140, R12:152 VGPR, pins hold; R13 showed multi-wave blocks make the
// allocator chase LDS-occupancy and spill pins). New split: i/f/g pinned
// (192 VGPR; live set ~225 < 256 cap) + ONLY o in LDS (16 KB -> 10 blocks/CU
// by LDS; VGPR ~225 -> 2 waves/SIMD). Zero in-loop weight L2 traffic, so
// extra occupancy is pure latency hiding (R8's poison mechanism absent).
// R12's occupancy blocker was its own 32 KB LDS (5 blocks/CU = 1.25/SIMD).
// ---------------------------------------------------------------------------
#define PINQ(wq) \
    asm volatile("" : "+v"(wq.x), "+v"(wq.y), "+v"(wq.z), "+v"(wq.w))

template <int L>
__global__ __launch_bounds__(64, 1) void lstm_scan(
    const float* __restrict__ w_hh)   // [2][G][64]
{
    const int l   = threadIdx.x;
    const int dir = (L == 0) ? (blockIdx.x & 1) : 0;
    const int b   = (L == 0) ? (int)(blockIdx.x >> 1) : (int)blockIdx.x;

    const float* wbase = w_hh + (size_t)dir * GG * HH;

    // o-row -> LDS: wo_lds[q*64 + l] = W[192 + l][quad q]. Lane stride 16B
    // -> 2-way bank aliasing = free (R10/R12: measured 0 conflicts). 16 KB.
    __shared__ __align__(16) float4 wo_lds[16 * 64];
    {
        const float4* po_ = (const float4*)(wbase + (size_t)(192 + l) * HH);
#pragma unroll
        for (int q = 0; q < 16; ++q) wo_lds[q * 64 + l] = po_[q];
    }

    // i/f/g rows: named quads, pinned resident (192 VGPR).
    const float4* pi_ = (const float4*)(wbase + (size_t)(0   + l) * HH);
    const float4* pf_ = (const float4*)(wbase + (size_t)(64  + l) * HH);
    const float4* pg_ = (const float4*)(wbase + (size_t)(128 + l) * HH);
    float4 wi0 = pi_[0],  wi1 = pi_[1],  wi2 = pi_[2],  wi3 = pi_[3],
           wi4 = pi_[4],  wi5 = pi_[5],  wi6 = pi_[6],  wi7 = pi_[7],
           wi8 = pi_[8],  wi9 = pi_[9],  wi10 = pi_[10], wi11 = pi_[11],
           wi12 = pi_[12], wi13 = pi_[13], wi14 = pi_[14], wi15 = pi_[15];
    float4 wf0 = pf_[0],  wf1 = pf_[1],  wf2 = pf_[2],  wf3 = pf_[3],
           wf4 = pf_[4],  wf5 = pf_[5],  wf6 = pf_[6],  wf7 = pf_[7],
           wf8 = pf_[8],  wf9 = pf_[9],  wf10 = pf_[10], wf11 = pf_[11],
           wf12 = pf_[12], wf13 = pf_[13], wf14 = pf_[14], wf15 = pf_[15];
    float4 wg0 = pg_[0],  wg1 = pg_[1],  wg2 = pg_[2],  wg3 = pg_[3],
           wg4 = pg_[4],  wg5 = pg_[5],  wg6 = pg_[6],  wg7 = pg_[7],
           wg8 = pg_[8],  wg9 = pg_[9],  wg10 = pg_[10], wg11 = pg_[11],
           wg12 = pg_[12], wg13 = pg_[13], wg14 = pg_[14], wg15 = pg_[15];
    PINQ(wi0);  PINQ(wi1);  PINQ(wi2);  PINQ(wi3);
    PINQ(wi4);  PINQ(wi5);  PINQ(wi6);  PINQ(wi7);
    PINQ(wi8);  PINQ(wi9);  PINQ(wi10); PINQ(wi11);
    PINQ(wi12); PINQ(wi13); PINQ(wi14); PINQ(wi15);
    PINQ(wf0);  PINQ(wf1);  PINQ(wf2);  PINQ(wf3);
    PINQ(wf4);  PINQ(wf5);  PINQ(wf6);  PINQ(wf7);
    PINQ(wf8);  PINQ(wf9);  PINQ(wf10); PINQ(wf11);
    PINQ(wf12); PINQ(wf13); PINQ(wf14); PINQ(wf15);
    PINQ(wg0);  PINQ(wg1);  PINQ(wg2);  PINQ(wg3);
    PINQ(wg4);  PINQ(wg5);  PINQ(wg6);  PINQ(wg7);
    PINQ(wg8);  PINQ(wg9);  PINQ(wg10); PINQ(wg11);
    PINQ(wg12); PINQ(wg13); PINQ(wg14); PINQ(wg15);

    __syncthreads();   // wo_lds visible

    const float* pre = (L == 0) ? (g_pre0 + (size_t)dir * TT * BB * GG) : g_pre1;

    float c = 0.f, h = 0.f;

    // 2-deep pre-gate prefetch pipeline (explicit register rotation).
    const int t0 = dir ? (TT - 1) : 0;
    const int t1 = dir ? (TT - 2) : 1;
    const float* pp0 = pre + ((size_t)t0 * BB + b) * GG;
    const float* pp1 = pre + ((size_t)t1 * BB + b) * GG;
    float ci0 = pp0[l], cf0 = pp0[64 + l], cg0 = pp0[128 + l], co0 = pp0[192 + l];
    float ci1 = pp1[l], cf1 = pp1[64 + l], cg1 = pp1[128 + l], co1 = pp1[192 + l];

    for (int s = 0; s < TT; ++s) {
        const int t = dir ? (TT - 1 - s) : s;

        // Issue prefetch for step s+2 (consumed two iterations from now).
        float ni = 0.f, nf = 0.f, ng = 0.f, no_ = 0.f;
        if (s + 2 < TT) {
            const int tn = dir ? (TT - 3 - s) : (s + 2);
            const float* np = pre + ((size_t)tn * BB + b) * GG;
            ni = np[l]; nf = np[64 + l]; ng = np[128 + l]; no_ = np[192 + l];
        }

        float ai = ci0, af = cf0, ag = cg0, ao = co0;

#define STEPQ(q) do {                                                        \
        const float4 woq = wo_lds[(q) * 64 + l];                             \
        float s0 = rlane(h, 4*q+0), s1 = rlane(h, 4*q+1),                    \
              s2 = rlane(h, 4*q+2), s3 = rlane(h, 4*q+3);                    \
        ai += s0*wi##q.x + s1*wi##q.y + s2*wi##q.z + s3*wi##q.w;             \
        af += s0*wf##q.x + s1*wf##q.y + s2*wf##q.z + s3*wf##q.w;             \
        ag += s0*wg##q.x + s1*wg##q.y + s2*wg##q.z + s3*wg##q.w;             \
        ao += s0*woq.x + s1*woq.y + s2*woq.z + s3*woq.w;                     \
    } while (0)

        STEPQ(0);  STEPQ(1);  STEPQ(2);  STEPQ(3);
        STEPQ(4);  STEPQ(5);  STEPQ(6);  STEPQ(7);
        STEPQ(8);  STEPQ(9);  STEPQ(10); STEPQ(11);
        STEPQ(12); STEPQ(13); STEPQ(14); STEPQ(15);
#undef STEPQ

        const float ig = fsigm(ai);
        const float fg = fsigm(af);
        const float gg = ftanh(ag);
        const float og = fsigm(ao);
        c = fg * c + ig * gg;
        h = og * ftanh(c);

        if (L == 0) {
            g_h1[((size_t)t * BB + b) * (2 * HH) + dir * HH + l] = h;  // coalesced 256B
        } else {
            if (s == TT - 1) g_hf[(size_t)b * HH + l] = h;
        }

        // Rotate the prefetch pipeline.
        ci0 = ci1; cf0 = cf1; cg0 = cg1; co0 = co1;
        ci1 = ni;  cf1 = nf;  cg1 = ng;  co1 = no_;
    }
}

// ---------------------------------------------------------------------------
// Layer-1 forward input pre-gates, v2.1 (proven correct in R8/R9): tiled GEMM.
// OUT[M=TT*BB][256] = H1[M][128] @ W^T + bias; OUT row m = t*BB+b.
// Tile 64m x 64n, K=128 one-shot: A row-major (+132-dword pad), B transposed
// [k][n] (+68-dword pad). Thread (ty,tx) computes 4m x 4n. 67 KB LDS.
// ---------------------------------------------------------------------------
__global__ __launch_bounds__(256, 2) void pre_gemm1(
    const float* __restrict__ w_ih,   // [2][G][128] (dir 0 used)
    const float* __restrict__ b_ih,
    const float* __restrict__ b_hh)
{
    __shared__ __align__(16) float As[64 * 132];   // [m][k], pad 132
    __shared__ __align__(16) float Bs[128 * 68];   // [k][n], pad 68

    const int tid   = threadIdx.x;
    const int mbase = (int)(blockIdx.x >> 2) * 64;
    const int n0    = (int)(blockIdx.x & 3) * 64;

    // Stage A: 64 rows x 32 k-quads = 2048 quads, 8 iters, coalesced.
#pragma unroll
    for (int i = 0; i < 8; ++i) {
        const int qid = tid + 256 * i;
        const int r = qid >> 5, q = qid & 31;
        float4 v = *(const float4*)(g_h1 + (size_t)(mbase + r) * 128 + q * 4);
        *(float4*)(&As[r * 132 + q * 4]) = v;
    }
    // Stage B transposed: 64 n-rows x 32 k-quads = 2048 quads, 8 iters.
#pragma unroll
    for (int i = 0; i < 8; ++i) {
        const int qid = tid + 256 * i;
        const int r = qid >> 5, q = qid & 31;   // r = local gate, q = k-quad
        float4 v = *(const float4*)(w_ih + (size_t)(n0 + r) * 128 + q * 4);
        Bs[(q * 4 + 0) * 68 + r] = v.x;
        Bs[(q * 4 + 1) * 68 + r] = v.y;
        Bs[(q * 4 + 2) * 68 + r] = v.z;
        Bs[(q * 4 + 3) * 68 + r] = v.w;
    }
    __syncthreads();

    const int tx = tid & 15, ty = tid >> 4;

    float4 c0 = make_float4(0.f, 0.f, 0.f, 0.f);
    float4 c1 = c0, c2 = c0, c3 = c0;

#pragma unroll 8
    for (int kq = 0; kq < 32; ++kq) {
        const float4 a0 = *(const float4*)&As[(ty * 4 + 0) * 132 + kq * 4];
        const float4 a1 = *(const float4*)&As[(ty * 4 + 1) * 132 + kq * 4];
        const float4 a2 = *(const float4*)&As[(ty * 4 + 2) * 132 + kq * 4];
        const float4 a3 = *(const float4*)&As[(ty * 4 + 3) * 132 + kq * 4];
        const float4 b0 = *(const float4*)&Bs[(kq * 4 + 0) * 68 + tx * 4];
        const float4 b1 = *(const float4*)&Bs[(kq * 4 + 1) * 68 + tx * 4];
        const float4 b2 = *(const float4*)&Bs[(kq * 4 + 2) * 68 + tx * 4];
        const float4 b3 = *(const float4*)&Bs[(kq * 4 + 3) * 68 + tx * 4];
        FMA4(c0, a0.x, b0); FMA4(c0, a0.y, b1); FMA4(c0, a0.z, b2); FMA4(c0, a0.w, b3);
        FMA4(c1, a1.x, b0); FMA4(c1, a1.y, b1); FMA4(c1, a1.z, b2); FMA4(c1, a1.w, b3);
        FMA4(c2, a2.x, b0); FMA4(c2, a2.y, b1); FMA4(c2, a2.z, b2); FMA4(c2, a2.w, b3);
        FMA4(c3, a3.x, b0); FMA4(c3, a3.y, b1); FMA4(c3, a3.z, b2); FMA4(c3, a3.w, b3);
    }

    float4 bias4;
    bias4.x = b_ih[n0 + tx * 4 + 0] + b_hh[n0 + tx * 4 + 0];
    bias4.y = b_ih[n0 + tx * 4 + 1] + b_hh[n0 + tx * 4 + 1];
    bias4.z = b_ih[n0 + tx * 4 + 2] + b_hh[n0 + tx * 4 + 2];
    bias4.w = b_ih[n0 + tx * 4 + 3] + b_hh[n0 + tx * 4 + 3];

    FMA4(c0, 1.f, bias4); FMA4(c1, 1.f, bias4);
    FMA4(c2, 1.f, bias4); FMA4(c3, 1.f, bias4);

    float* ob = g_pre1 + (size_t)(mbase + ty * 4) * GG + n0 + tx * 4;
    *(float4*)(ob + 0 * (size_t)GG) = c0;
    *(float4*)(ob + 1 * (size_t)GG) = c1;
    *(float4*)(ob + 2 * (size_t)GG) = c2;
    *(float4*)(ob + 3 * (size_t)GG) = c3;
}

// ---------------------------------------------------------------------------
// Layer 1 backward single step (zero state on h1[T-1]) + FC head (unchanged).
// ---------------------------------------------------------------------------
#define FMAC4(W, P0, P1, P2, P3, K) do{                                   \
    float4 v_;                                                           \
    v_ = (P0)[K]; acc0 += W.x*v_.x; acc0 += W.y*v_.y; acc0 += W.z*v_.z; acc0 += W.w*v_.w; \
    v_ = (P1)[K]; acc1 += W.x*v_.x; acc1 += W.y*v_.y; acc1 += W.z*v_.z; acc1 += W.w*v_.w; \
    v_ = (P2)[K]; acc2 += W.x*v_.x; acc2 += W.y*v_.y; acc2 += W.z*v_.z; acc2 += W.w*v_.w; \
    v_ = (P3)[K]; acc3 += W.x*v_.x; acc3 += W.y*v_.y; acc3 += W.z*v_.z; acc3 += W.w*v_.w; \
}while(0)

__global__ __launch_bounds__(256, 2) void lstm_final(
    const float* __restrict__ w_ih,   // [2][G][128] (dir 1)
    const float* __restrict__ b_ih,
    const float* __restrict__ b_hh,
    const float* __restrict__ fc_w,   // [2][128]
    const float* __restrict__ fc_b,   // [2]
    float* __restrict__ out)          // [B][2]
{
    const int tid = threadIdx.x;
    const int b0  = blockIdx.x * 4;

    __shared__ __align__(16) float x_lds[4][128];
    __shared__ __align__(16) float gact[4][GG];
    __shared__ __align__(16) float last[4][128];

#pragma unroll
    for (int r = 0; r < 2; ++r) {
        int idx = tid + r * 256;
        int b = idx >> 7, col = idx & 127;
        x_lds[b][col] = g_h1[((size_t)(TT - 1) * BB + (b0 + b)) * 128 + col];
    }

    const float4* p = (const float4*)(w_ih + ((size_t)GG + tid) * 128);
    float4 w0 = p[0],  w1 = p[1],  w2 = p[2],  w3 = p[3],  w4 = p[4],  w5 = p[5],
           w6 = p[6],  w7 = p[7],  w8 = p[8],  w9 = p[9],  w10 = p[10], w11 = p[11],
           w12 = p[12], w13 = p[13], w14 = p[14], w15 = p[15], w16 = p[16], w17 = p[17],
           w18 = p[18], w19 = p[19], w20 = p[20], w21 = p[21], w22 = p[22], w23 = p[23],
           w24 = p[24], w25 = p[25], w26 = p[26], w27 = p[27], w28 = p[28], w29 = p[29],
           w30 = p[30], w31 = p[31];
    const float bias = b_ih[GG + tid] + b_hh[GG + tid];
    __syncthreads();

    const float4* xb0 = (const float4*)x_lds[0];
    const float4* xb1 = (const float4*)x_lds[1];
    const float4* xb2 = (const float4*)x_lds[2];
    const float4* xb3 = (const float4*)x_lds[3];

    float acc0 = bias, acc1 = bias, acc2 = bias, acc3 = bias;
    FMAC4(w0, xb0, xb1, xb2, xb3, 0);   FMAC4(w1, xb0, xb1, xb2, xb3, 1);
    FMAC4(w2, xb0, xb1, xb2, xb3, 2);   FMAC4(w3, xb0, xb1, xb2, xb3, 3);
    FMAC4(w4, xb0, xb1, xb2, xb3, 4);   FMAC4(w5, xb0, xb1, xb2, xb3, 5);
    FMAC4(w6, xb0, xb1, xb2, xb3, 6);   FMAC4(w7, xb0, xb1, xb2, xb3, 7);
    FMAC4(w8, xb0, xb1, xb2, xb3, 8);   FMAC4(w9, xb0, xb1, xb2, xb3, 9);
    FMAC4(w10, xb0, xb1, xb2, xb3, 10); FMAC4(w11, xb0, xb1, xb2, xb3, 11);
    FMAC4(w12, xb0, xb1, xb2, xb3, 12); FMAC4(w13, xb0, xb1, xb2, xb3, 13);
    FMAC4(w14, xb0, xb1, xb2, xb3, 14); FMAC4(w15, xb0, xb1, xb2, xb3, 15);
    FMAC4(w16, xb0, xb1, xb2, xb3, 16); FMAC4(w17, xb0, xb1, xb2, xb3, 17);
    FMAC4(w18, xb0, xb1, xb2, xb3, 18); FMAC4(w19, xb0, xb1, xb2, xb3, 19);
    FMAC4(w20, xb0, xb1, xb2, xb3, 20); FMAC4(w21, xb0, xb1, xb2, xb3, 21);
    FMAC4(w22, xb0, xb1, xb2, xb3, 22); FMAC4(w23, xb0, xb1, xb2, xb3, 23);
    FMAC4(w24, xb0, xb1, xb2, xb3, 24); FMAC4(w25, xb0, xb1, xb2, xb3, 25);
    FMAC4(w26, xb0, xb1, xb2, xb3, 26); FMAC4(w27, xb0, xb1, xb2, xb3, 27);
    FMAC4(w28, xb0, xb1, xb2, xb3, 28); FMAC4(w29, xb0, xb1, xb2, xb3, 29);
    FMAC4(w30, xb0, xb1, xb2, xb3, 30); FMAC4(w31, xb0, xb1, xb2, xb3, 31);

    const bool is_g = ((tid >> 6) == 2);
    gact[0][tid] = is_g ? ftanh(acc0) : fsigm(acc0);
    gact[1][tid] = is_g ? ftanh(acc1) : fsigm(acc1);
    gact[2][tid] = is_g ? ftanh(acc2) : fsigm(acc2);
    gact[3][tid] = is_g ? ftanh(acc3) : fsigm(acc3);
    __syncthreads();

    {
        const int cb = tid >> 6, cj = tid & 63;
        float ig = gact[cb][cj];
        float gg = gact[cb][2 * HH + cj];
        float og = gact[cb][3 * HH + cj];
        float c = ig * gg;
        float h = og * ftanh(c);
        last[cb][HH + cj] = h;
        last[cb][cj] = g_hf[(size_t)(b0 + cb) * HH + cj];
    }
    __syncthreads();

    if (tid < 8) {
        int b = tid >> 1, o = tid & 1;
        float a = fc_b[o];
#pragma unroll
        for (int j = 0; j < 128; ++j) a += fc_w[o * 128 + j] * last[b][j];
        out[(size_t)(b0 + b) * 2 + o] = a;
    }
}

extern "C" void kernel_launch(void* const* d_in, const int* in_sizes, int n_in,
                              void* d_out, int out_size, void* d_ws, size_t ws_size,
                              hipStream_t stream) {
    const float* x     = (const float*)d_in[0];
    const float* w_ih0 = (const float*)d_in[1];
    const float* w_hh0 = (const float*)d_in[2];
    const float* b_ih0 = (const float*)d_in[3];
    const float* b_hh0 = (const float*)d_in[4];
    const float* w_ih1 = (const float*)d_in[5];
    const float* w_hh1 = (const float*)d_in[6];
    const float* b_ih1 = (const float*)d_in[7];
    const float* b_hh1 = (const float*)d_in[8];
    const float* fc_w  = (const float*)d_in[9];
    const float* fc_b  = (const float*)d_in[10];
    float* out = (float*)d_out;

    pre_gemm0<<<2048, 256, 0, stream>>>(x, w_ih0, b_ih0, b_hh0);
    lstm_scan<0><<<2048, 64, 0, stream>>>(w_hh0);
    pre_gemm1<<<32768, 256, 0, stream>>>(w_ih1, b_ih1, b_hh1);
    lstm_scan<1><<<1024, 64, 0, stream>>>(w_hh1);
    lstm_final<<<256, 256, 0, stream>>>(w_ih1, b_ih1, b_hh1, fc_w, fc_b, out);
}

// Round 15
// 2447.142 us; speedup vs baseline: 2.1962x; 1.2243x over previous
//
#include <hip/hip_runtime.h>

#define TT 512
#define BB 1024
#define FF 32
#define HH 64
#define GG 256   // 4*H gates per direction

// Static device scratch (ws_size-independent). Fully overwritten every call.
// R15 relayout: ALL scratch is batch-major so every hot access streams
// sequentially (t-major had 1MB-stride 1KB chunks -> DRAM-page bound).
__device__ float g_h1[(size_t)BB * TT * 2 * HH];   // [B][T][128] layer-1 input
__device__ float g_pre0[(size_t)2 * BB * TT * GG]; // [dir][B][T][256] layer-0 pre-gates
__device__ float g_pre1[(size_t)BB * TT * GG];     // [B][T][256] layer-1 fwd pre-gates
__device__ float g_hf[(size_t)BB * HH];            // [B][64] final fwd h of layer1

__device__ __forceinline__ float fsigm(float x) {
    float e = __builtin_amdgcn_exp2f(x * -1.44269504088896f);
    return __builtin_amdgcn_rcpf(1.0f + e);
}
__device__ __forceinline__ float ftanh(float x) {
    float e = __builtin_amdgcn_exp2f(x * -2.88539008177793f);
    return 2.0f * __builtin_amdgcn_rcpf(1.0f + e) - 1.0f;
}
// Wave-uniform broadcast via v_readlane (VALU, zero LDS-pipe cost).
__device__ __forceinline__ float rlane(float v, int l) {
    return __int_as_float(__builtin_amdgcn_readlane(__float_as_int(v), l));
}

#define FMA4(c, s, b) do { c.x += (s)*(b).x; c.y += (s)*(b).y; \
                           c.z += (s)*(b).z; c.w += (s)*(b).w; } while (0)

// ---------------------------------------------------------------------------
// Layer-0 input pre-gates — original structure; output now [dir][b][t][gate]
// so the 8 t-rows per tc are 8 KB CONTIGUOUS (was 8x1KB at 1MB stride).
// ---------------------------------------------------------------------------
__global__ __launch_bounds__(256, 4) void pre_gemm0(
    const float* __restrict__ x,      // [B][T][F]
    const float* __restrict__ w_ih,   // [2][G][F]
    const float* __restrict__ b_ih,
    const float* __restrict__ b_hh)
{
    const int tid = threadIdx.x;          // gate
    const int b   = blockIdx.x >> 1;
    const int dir = blockIdx.x & 1;

    __shared__ __align__(16) float4 w4[8 * 256];    // [kq][gate], 32 KB
    __shared__ __align__(16) float xbuf[2][256];    // 8 t-rows x 32 f, dbuf

    const float4* wsrc = (const float4*)(w_ih + ((size_t)dir * GG + tid) * FF);
#pragma unroll
    for (int kq = 0; kq < 8; ++kq) w4[kq * 256 + tid] = wsrc[kq];
    const float bias = b_ih[dir * GG + tid] + b_hh[dir * GG + tid];

    const float* xbase = x + (size_t)b * TT * FF;
    xbuf[0][tid] = xbase[tid];            // tile 0 (rows 0..7), coalesced

    for (int tc = 0; tc < 64; ++tc) {
        const int cur = tc & 1;
        __syncthreads();   // xbuf[cur] ready; prev reads of xbuf[1-cur] done

        float vnext = 0.f;
        if (tc + 1 < 64) vnext = xbase[(tc + 1) * 256 + tid];   // coalesced

        float a0 = bias, a1 = bias, a2 = bias, a3 = bias,
              a4 = bias, a5 = bias, a6 = bias, a7 = bias;
#pragma unroll
        for (int kq = 0; kq < 8; ++kq) {
            float4 wq = w4[kq * 256 + tid];
            const float4* xr = (const float4*)xbuf[cur];
            float4 q;
            q = xr[0 * 8 + kq]; a0 += q.x*wq.x + q.y*wq.y + q.z*wq.z + q.w*wq.w;
            q = xr[1 * 8 + kq]; a1 += q.x*wq.x + q.y*wq.y + q.z*wq.z + q.w*wq.w;
            q = xr[2 * 8 + kq]; a2 += q.x*wq.x + q.y*wq.y + q.z*wq.z + q.w*wq.w;
            q = xr[3 * 8 + kq]; a3 += q.x*wq.x + q.y*wq.y + q.z*wq.z + q.w*wq.w;
            q = xr[4 * 8 + kq]; a4 += q.x*wq.x + q.y*wq.y + q.z*wq.z + q.w*wq.w;
            q = xr[5 * 8 + kq]; a5 += q.x*wq.x + q.y*wq.y + q.z*wq.z + q.w*wq.w;
            q = xr[6 * 8 + kq]; a6 += q.x*wq.x + q.y*wq.y + q.z*wq.z + q.w*wq.w;
            q = xr[7 * 8 + kq]; a7 += q.x*wq.x + q.y*wq.y + q.z*wq.z + q.w*wq.w;
        }
        // [dir][b][t][gate]: 8 consecutive t-rows -> 8 KB contiguous.
        float* op = g_pre0 + (((size_t)dir * BB + b) * TT + tc * 8) * GG + tid;
        op[0 * GG] = a0; op[1 * GG] = a1; op[2 * GG] = a2; op[3 * GG] = a3;
        op[4 * GG] = a4; op[5 * GG] = a5; op[6 * GG] = a6; op[7 * GG] = a7;

        if (tc + 1 < 64) xbuf[1 - cur][tid] = vnext;
    }
}

// ---------------------------------------------------------------------------
// Recurrent scan — R9-EXACT structure (proven best: 990us; R10-R14 closed all
// perturbations: B2 spills, multi-wave blocks break pins, >128 pins spill,
// g/o LDS is neutral). Only change: batch-major pre-gate/h1 indexing —
// per-step reads are now a 1KB SEQUENTIAL stream (was 1MB-stride scatter),
// h1 writes 256B at 512B stride (was 512KB stride).
// i/f rows pinned (128 VGPR resident), g/o arrays (L2 remat, accepted).
// ---------------------------------------------------------------------------
#define PINQ(wq) \
    asm volatile("" : "+v"(wq.x), "+v"(wq.y), "+v"(wq.z), "+v"(wq.w))

template <int L>
__global__ __launch_bounds__(64, 1) void lstm_scan(
    const float* __restrict__ w_hh)   // [2][G][64]
{
    const int l   = threadIdx.x;
    const int dir = (L == 0) ? (blockIdx.x & 1) : 0;
    const int b   = (L == 0) ? (int)(blockIdx.x >> 1) : (int)blockIdx.x;

    const float* wbase = w_hh + (size_t)dir * GG * HH;

    // i/f rows: named quads, pinned resident (128 VGPR, R9-proven).
    const float4* pi_ = (const float4*)(wbase + (size_t)(0  + l) * HH);
    const float4* pf_ = (const float4*)(wbase + (size_t)(64 + l) * HH);
    float4 wi0 = pi_[0],  wi1 = pi_[1],  wi2 = pi_[2],  wi3 = pi_[3],
           wi4 = pi_[4],  wi5 = pi_[5],  wi6 = pi_[6],  wi7 = pi_[7],
           wi8 = pi_[8],  wi9 = pi_[9],  wi10 = pi_[10], wi11 = pi_[11],
           wi12 = pi_[12], wi13 = pi_[13], wi14 = pi_[14], wi15 = pi_[15];
    float4 wf0 = pf_[0],  wf1 = pf_[1],  wf2 = pf_[2],  wf3 = pf_[3],
           wf4 = pf_[4],  wf5 = pf_[5],  wf6 = pf_[6],  wf7 = pf_[7],
           wf8 = pf_[8],  wf9 = pf_[9],  wf10 = pf_[10], wf11 = pf_[11],
           wf12 = pf_[12], wf13 = pf_[13], wf14 = pf_[14], wf15 = pf_[15];
    PINQ(wi0);  PINQ(wi1);  PINQ(wi2);  PINQ(wi3);
    PINQ(wi4);  PINQ(wi5);  PINQ(wi6);  PINQ(wi7);
    PINQ(wi8);  PINQ(wi9);  PINQ(wi10); PINQ(wi11);
    PINQ(wi12); PINQ(wi13); PINQ(wi14); PINQ(wi15);
    PINQ(wf0);  PINQ(wf1);  PINQ(wf2);  PINQ(wf3);
    PINQ(wf4);  PINQ(wf5);  PINQ(wf6);  PINQ(wf7);
    PINQ(wf8);  PINQ(wf9);  PINQ(wf10); PINQ(wf11);
    PINQ(wf12); PINQ(wf13); PINQ(wf14); PINQ(wf15);

    // g/o rows: arrays, allocator remats from L2 (accepted, R9 behavior).
    float4 wg[16], wo[16];
    {
        const float4* pg_ = (const float4*)(wbase + (size_t)(128 + l) * HH);
        const float4* po_ = (const float4*)(wbase + (size_t)(192 + l) * HH);
#pragma unroll
        for (int q = 0; q < 16; ++q) { wg[q] = pg_[q]; wo[q] = po_[q]; }
    }

    // Batch-major base: this wave's pre-gate rows are TT x 1KB, sequential.
    const float* pre = (L == 0)
        ? (g_pre0 + ((size_t)(dir * BB + b)) * TT * GG)
        : (g_pre1 + (size_t)b * TT * GG);

    float c = 0.f, h = 0.f;

    // 2-deep pre-gate prefetch pipeline (explicit register rotation).
    const int t0 = dir ? (TT - 1) : 0;
    const int t1 = dir ? (TT - 2) : 1;
    const float* pp0 = pre + (size_t)t0 * GG;
    const float* pp1 = pre + (size_t)t1 * GG;
    float ci0 = pp0[l], cf0 = pp0[64 + l], cg0 = pp0[128 + l], co0 = pp0[192 + l];
    float ci1 = pp1[l], cf1 = pp1[64 + l], cg1 = pp1[128 + l], co1 = pp1[192 + l];

    for (int s = 0; s < TT; ++s) {
        const int t = dir ? (TT - 1 - s) : s;

        // Issue prefetch for step s+2 (consumed two iterations from now).
        float ni = 0.f, nf = 0.f, ng = 0.f, no_ = 0.f;
        if (s + 2 < TT) {
            const int tn = dir ? (TT - 3 - s) : (s + 2);
            const float* np = pre + (size_t)tn * GG;
            ni = np[l]; nf = np[64 + l]; ng = np[128 + l]; no_ = np[192 + l];
        }

        float ai = ci0, af = cf0, ag = cg0, ao = co0;

#define STEPQ(q) do {                                                        \
        float s0 = rlane(h, 4*q+0), s1 = rlane(h, 4*q+1),                    \
              s2 = rlane(h, 4*q+2), s3 = rlane(h, 4*q+3);                    \
        ai += s0*wi##q.x + s1*wi##q.y + s2*wi##q.z + s3*wi##q.w;             \
        af += s0*wf##q.x + s1*wf##q.y + s2*wf##q.z + s3*wf##q.w;             \
        ag += s0*wg[q].x + s1*wg[q].y + s2*wg[q].z + s3*wg[q].w;             \
        ao += s0*wo[q].x + s1*wo[q].y + s2*wo[q].z + s3*wo[q].w;             \
    } while (0)

        STEPQ(0);  STEPQ(1);  STEPQ(2);  STEPQ(3);
        STEPQ(4);  STEPQ(5);  STEPQ(6);  STEPQ(7);
        STEPQ(8);  STEPQ(9);  STEPQ(10); STEPQ(11);
        STEPQ(12); STEPQ(13); STEPQ(14); STEPQ(15);
#undef STEPQ

        const float ig = fsigm(ai);
        const float fg = fsigm(af);
        const float gg = ftanh(ag);
        const float og = fsigm(ao);
        c = fg * c + ig * gg;
        h = og * ftanh(c);

        if (L == 0) {
            // [b][t][dir*64+l]: 256B at 512B stride, b-local streaming.
            g_h1[((size_t)b * TT + t) * (2 * HH) + dir * HH + l] = h;
        } else {
            if (s == TT - 1) g_hf[(size_t)b * HH + l] = h;
        }

        // Rotate the prefetch pipeline.
        ci0 = ci1; cf0 = cf1; cg0 = cg1; co0 = co1;
        ci1 = ni;  cf1 = nf;  cg1 = ng;  co1 = no_;
    }
}

// ---------------------------------------------------------------------------
// Layer-1 forward input pre-gates, v2.1 (proven correct): tiled GEMM.
// Formulas UNCHANGED — m is now b*TT+t (batch-major); 64-tiles never cross b
// (512 % 64 == 0). A reads 32KB contiguous g_h1; writes contiguous g_pre1.
// ---------------------------------------------------------------------------
__global__ __launch_bounds__(256, 2) void pre_gemm1(
    const float* __restrict__ w_ih,   // [2][G][128] (dir 0 used)
    const float* __restrict__ b_ih,
    const float* __restrict__ b_hh)
{
    __shared__ __align__(16) float As[64 * 132];   // [m][k], pad 132
    __shared__ __align__(16) float Bs[128 * 68];   // [k][n], pad 68

    const int tid   = threadIdx.x;
    const int mbase = (int)(blockIdx.x >> 2) * 64;
    const int n0    = (int)(blockIdx.x & 3) * 64;

    // Stage A: 64 rows x 32 k-quads = 2048 quads, 8 iters, coalesced.
#pragma unroll
    for (int i = 0; i < 8; ++i) {
        const int qid = tid + 256 * i;
        const int r = qid >> 5, q = qid & 31;
        float4 v = *(const float4*)(g_h1 + (size_t)(mbase + r) * 128 + q * 4);
        *(float4*)(&As[r * 132 + q * 4]) = v;
    }
    // Stage B transposed: 64 n-rows x 32 k-quads = 2048 quads, 8 iters.
#pragma unroll
    for (int i = 0; i < 8; ++i) {
        const int qid = tid + 256 * i;
        const int r = qid >> 5, q = qid & 31;   // r = local gate, q = k-quad
        float4 v = *(const float4*)(w_ih + (size_t)(n0 + r) * 128 + q * 4);
        Bs[(q * 4 + 0) * 68 + r] = v.x;
        Bs[(q * 4 + 1) * 68 + r] = v.y;
        Bs[(q * 4 + 2) * 68 + r] = v.z;
        Bs[(q * 4 + 3) * 68 + r] = v.w;
    }
    __syncthreads();

    const int tx = tid & 15, ty = tid >> 4;

    float4 c0 = make_float4(0.f, 0.f, 0.f, 0.f);
    float4 c1 = c0, c2 = c0, c3 = c0;

#pragma unroll 8
    for (int kq = 0; kq < 32; ++kq) {
        const float4 a0 = *(const float4*)&As[(ty * 4 + 0) * 132 + kq * 4];
        const float4 a1 = *(const float4*)&As[(ty * 4 + 1) * 132 + kq * 4];
        const float4 a2 = *(const float4*)&As[(ty * 4 + 2) * 132 + kq * 4];
        const float4 a3 = *(const float4*)&As[(ty * 4 + 3) * 132 + kq * 4];
        const float4 b0 = *(const float4*)&Bs[(kq * 4 + 0) * 68 + tx * 4];
        const float4 b1 = *(const float4*)&Bs[(kq * 4 + 1) * 68 + tx * 4];
        const float4 b2 = *(const float4*)&Bs[(kq * 4 + 2) * 68 + tx * 4];
        const float4 b3 = *(const float4*)&Bs[(kq * 4 + 3) * 68 + tx * 4];
        FMA4(c0, a0.x, b0); FMA4(c0, a0.y, b1); FMA4(c0, a0.z, b2); FMA4(c0, a0.w, b3);
        FMA4(c1, a1.x, b0); FMA4(c1, a1.y, b1); FMA4(c1, a1.z, b2); FMA4(c1, a1.w, b3);
        FMA4(c2, a2.x, b0); FMA4(c2, a2.y, b1); FMA4(c2, a2.z, b2); FMA4(c2, a2.w, b3);
        FMA4(c3, a3.x, b0); FMA4(c3, a3.y, b1); FMA4(c3, a3.z, b2); FMA4(c3, a3.w, b3);
    }

    float4 bias4;
    bias4.x = b_ih[n0 + tx * 4 + 0] + b_hh[n0 + tx * 4 + 0];
    bias4.y = b_ih[n0 + tx * 4 + 1] + b_hh[n0 + tx * 4 + 1];
    bias4.z = b_ih[n0 + tx * 4 + 2] + b_hh[n0 + tx * 4 + 2];
    bias4.w = b_ih[n0 + tx * 4 + 3] + b_hh[n0 + tx * 4 + 3];

    FMA4(c0, 1.f, bias4); FMA4(c1, 1.f, bias4);
    FMA4(c2, 1.f, bias4); FMA4(c3, 1.f, bias4);

    float* ob = g_pre1 + (size_t)(mbase + ty * 4) * GG + n0 + tx * 4;
    *(float4*)(ob + 0 * (size_t)GG) = c0;
    *(float4*)(ob + 1 * (size_t)GG) = c1;
    *(float4*)(ob + 2 * (size_t)GG) = c2;
    *(float4*)(ob + 3 * (size_t)GG) = c3;
}

// ---------------------------------------------------------------------------
// Layer 1 backward single step (zero state on h1[T-1]) + FC head.
// Only change: g_h1 read uses batch-major index.
// ---------------------------------------------------------------------------
#define FMAC4(W, P0, P1, P2, P3, K) do{                                   \
    float4 v_;                                                           \
    v_ = (P0)[K]; acc0 += W.x*v_.x; acc0 += W.y*v_.y; acc0 += W.z*v_.z; acc0 += W.w*v_.w; \
    v_ = (P1)[K]; acc1 += W.x*v_.x; acc1 += W.y*v_.y; acc1 += W.z*v_.z; acc1 += W.w*v_.w; \
    v_ = (P2)[K]; acc2 += W.x*v_.x; acc2 += W.y*v_.y; acc2 += W.z*v_.z; acc2 += W.w*v_.w; \
    v_ = (P3)[K]; acc3 += W.x*v_.x; acc3 += W.y*v_.y; acc3 += W.z*v_.z; acc3 += W.w*v_.w; \
}while(0)

__global__ __launch_bounds__(256, 2) void lstm_final(
    const float* __restrict__ w_ih,   // [2][G][128] (dir 1)
    const float* __restrict__ b_ih,
    const float* __restrict__ b_hh,
    const float* __restrict__ fc_w,   // [2][128]
    const float* __restrict__ fc_b,   // [2]
    float* __restrict__ out)          // [B][2]
{
    const int tid = threadIdx.x;
    const int b0  = blockIdx.x * 4;

    __shared__ __align__(16) float x_lds[4][128];
    __shared__ __align__(16) float gact[4][GG];
    __shared__ __align__(16) float last[4][128];

#pragma unroll
    for (int r = 0; r < 2; ++r) {
        int idx = tid + r * 256;
        int b = idx >> 7, col = idx & 127;
        x_lds[b][col] = g_h1[((size_t)(b0 + b) * TT + (TT - 1)) * 128 + col];
    }

    const float4* p = (const float4*)(w_ih + ((size_t)GG + tid) * 128);
    float4 w0 = p[0],  w1 = p[1],  w2 = p[2],  w3 = p[3],  w4 = p[4],  w5 = p[5],
           w6 = p[6],  w7 = p[7],  w8 = p[8],  w9 = p[9],  w10 = p[10], w11 = p[11],
           w12 = p[12], w13 = p[13], w14 = p[14], w15 = p[15], w16 = p[16], w17 = p[17],
           w18 = p[18], w19 = p[19], w20 = p[20], w21 = p[21], w22 = p[22], w23 = p[23],
           w24 = p[24], w25 = p[25], w26 = p[26], w27 = p[27], w28 = p[28], w29 = p[29],
           w30 = p[30], w31 = p[31];
    const float bias = b_ih[GG + tid] + b_hh[GG + tid];
    __syncthreads();

    const float4* xb0 = (const float4*)x_lds[0];
    const float4* xb1 = (const float4*)x_lds[1];
    const float4* xb2 = (const float4*)x_lds[2];
    const float4* xb3 = (const float4*)x_lds[3];

    float acc0 = bias, acc1 = bias, acc2 = bias, acc3 = bias;
    FMAC4(w0, xb0, xb1, xb2, xb3, 0);   FMAC4(w1, xb0, xb1, xb2, xb3, 1);
    FMAC4(w2, xb0, xb1, xb2, xb3, 2);   FMAC4(w3, xb0, xb1, xb2, xb3, 3);
    FMAC4(w4, xb0, xb1, xb2, xb3, 4);   FMAC4(w5, xb0, xb1, xb2, xb3, 5);
    FMAC4(w6, xb0, xb1, xb2, xb3, 6);   FMAC4(w7, xb0, xb1, xb2, xb3, 7);
    FMAC4(w8, xb0, xb1, xb2, xb3, 8);   FMAC4(w9, xb0, xb1, xb2, xb3, 9);
    FMAC4(w10, xb0, xb1, xb2, xb3, 10); FMAC4(w11, xb0, xb1, xb2, xb3, 11);
    FMAC4(w12, xb0, xb1, xb2, xb3, 12); FMAC4(w13, xb0, xb1, xb2, xb3, 13);
    FMAC4(w14, xb0, xb1, xb2, xb3, 14); FMAC4(w15, xb0, xb1, xb2, xb3, 15);
    FMAC4(w16, xb0, xb1, xb2, xb3, 16); FMAC4(w17, xb0, xb1, xb2, xb3, 17);
    FMAC4(w18, xb0, xb1, xb2, xb3, 18); FMAC4(w19, xb0, xb1, xb2, xb3, 19);
    FMAC4(w20, xb0, xb1, xb2, xb3, 20); FMAC4(w21, xb0, xb1, xb2, xb3, 21);
    FMAC4(w22, xb0, xb1, xb2, xb3, 22); FMAC4(w23, xb0, xb1, xb2, xb3, 23);
    FMAC4(w24, xb0, xb1, xb2, xb3, 24); FMAC4(w25, xb0, xb1, xb2, xb3, 25);
    FMAC4(w26, xb0, xb1, xb2, xb3, 26); FMAC4(w27, xb0, xb1, xb2, xb3, 27);
    FMAC4(w28, xb0, xb1, xb2, xb3, 28); FMAC4(w29, xb0, xb1, xb2, xb3, 29);
    FMAC4(w30, xb0, xb1, xb2, xb3, 30); FMAC4(w31, xb0, xb1, xb2, xb3, 31);

    const bool is_g = ((tid >> 6) == 2);
    gact[0][tid] = is_g ? ftanh(acc0) : fsigm(acc0);
    gact[1][tid] = is_g ? ftanh(acc1) : fsigm(acc1);
    gact[2][tid] = is_g ? ftanh(acc2) : fsigm(acc2);
    gact[3][tid] = is_g ? ftanh(acc3) : fsigm(acc3);
    __syncthreads();

    {
        const int cb = tid >> 6, cj = tid & 63;
        float ig = gact[cb][cj];
        float gg = gact[cb][2 * HH + cj];
        float og = gact[cb][3 * HH + cj];
        float c = ig * gg;
        float h = og * ftanh(c);
        last[cb][HH + cj] = h;
        last[cb][cj] = g_hf[(size_t)(b0 + cb) * HH + cj];
    }
    __syncthreads();

    if (tid < 8) {
        int b = tid >> 1, o = tid & 1;
        float a = fc_b[o];
#pragma unroll
        for (int j = 0; j < 128; ++j) a += fc_w[o * 128 + j] * last[b][j];
        out[(size_t)(b0 + b) * 2 + o] = a;
    }
}

extern "C" void kernel_launch(void* const* d_in, const int* in_sizes, int n_in,
                              void* d_out, int out_size, void* d_ws, size_t ws_size,
                              hipStream_t stream) {
    const float* x     = (const float*)d_in[0];
    const float* w_ih0 = (const float*)d_in[1];
    const float* w_hh0 = (const float*)d_in[2];
    const float* b_ih0 = (const float*)d_in[3];
    const float* b_hh0 = (const float*)d_in[4];
    const float* w_ih1 = (const float*)d_in[5];
    const float* w_hh1 = (const float*)d_in[6];
    const float* b_ih1 = (const float*)d_in[7];
    const float* b_hh1 = (const float*)d_in[8];
    const float* fc_w  = (const float*)d_in[9];
    const float* fc_b  = (const float*)d_in[10];
    float* out = (float*)d_out;

    pre_gemm0<<<2048, 256, 0, stream>>>(x, w_ih0, b_ih0, b_hh0);
    lstm_scan<0><<<2048, 64, 0, stream>>>(w_hh0);
    pre_gemm1<<<32768, 256, 0, stream>>>(w_ih1, b_ih1, b_hh1);
    lstm_scan<1><<<1024, 64, 0, stream>>>(w_hh1);
    lstm_final<<<256, 256, 0, stream>>>(w_ih1, b_ih1, b_hh1, fc_w, fc_b, out);
}